// Round 2
// baseline (1702.497 us; speedup 1.0000x reference)
//
#include <hip/hip_runtime.h>
#include <hip/hip_bf16.h>

#define F 128
#define NN 100000
#define SCAN_B 1024

// ---------------------------------------------------------------------------
// CSR build: cnt -> exclusive scan -> cursor fill
// ---------------------------------------------------------------------------
__global__ void count_kernel(const int* __restrict__ dst, int* __restrict__ cnt, int E) {
    int i = blockIdx.x * blockDim.x + threadIdx.x;
    if (i < E) atomicAdd(&cnt[dst[i]], 1);
}

// per-block exclusive scan of SCAN_B elements; block totals to bsum
__global__ __launch_bounds__(SCAN_B) void scanA(const int* __restrict__ cnt,
                                                int* __restrict__ offs,
                                                int* __restrict__ bsum, int n) {
    __shared__ int s[SCAN_B];
    int gid = blockIdx.x * SCAN_B + threadIdx.x;
    int v = (gid < n) ? cnt[gid] : 0;
    s[threadIdx.x] = v;
    __syncthreads();
    for (int d = 1; d < SCAN_B; d <<= 1) {
        int t = (threadIdx.x >= d) ? s[threadIdx.x - d] : 0;
        __syncthreads();
        s[threadIdx.x] += t;
        __syncthreads();
    }
    if (gid < n) offs[gid] = s[threadIdx.x] - v;  // exclusive
    if (threadIdx.x == SCAN_B - 1) bsum[blockIdx.x] = s[SCAN_B - 1];
}

// exclusive scan of block sums (nb <= SCAN_B) in one block
__global__ __launch_bounds__(SCAN_B) void scanB(int* bsum, int nb) {
    __shared__ int s[SCAN_B];
    int v = (threadIdx.x < nb) ? bsum[threadIdx.x] : 0;
    s[threadIdx.x] = v;
    __syncthreads();
    for (int d = 1; d < SCAN_B; d <<= 1) {
        int t = (threadIdx.x >= d) ? s[threadIdx.x - d] : 0;
        __syncthreads();
        s[threadIdx.x] += t;
        __syncthreads();
    }
    if (threadIdx.x < nb) bsum[threadIdx.x] = s[threadIdx.x] - v;
}

// offs += bsum[block]; cur = offs; one thread writes offs[n] = E
__global__ __launch_bounds__(SCAN_B) void scanC(int* __restrict__ offs,
                                                const int* __restrict__ bsum,
                                                int* __restrict__ cur, int n, int E) {
    int gid = blockIdx.x * SCAN_B + threadIdx.x;
    if (gid < n) {
        int o = offs[gid] + bsum[blockIdx.x];
        offs[gid] = o;
        cur[gid] = o;
    }
    if (gid == n) offs[n] = E;
}

__global__ void fill_kernel(const int* __restrict__ src, const int* __restrict__ dst,
                            int* __restrict__ cur, int* __restrict__ csr, int E) {
    int i = blockIdx.x * blockDim.x + threadIdx.x;
    if (i < E) {
        int p = atomicAdd(&cur[dst[i]], 1);
        csr[p] = src[i];
    }
}

// ---------------------------------------------------------------------------
// type helpers (fp32 / bf16 node features)
// ---------------------------------------------------------------------------
__device__ __forceinline__ float2 load2(const float* p) { return *(const float2*)p; }
__device__ __forceinline__ float2 load2(const __hip_bfloat16* p) {
    __hip_bfloat162 v = *(const __hip_bfloat162*)p;
    return make_float2(__bfloat162float(v.x), __bfloat162float(v.y));
}
__device__ __forceinline__ float load1(const float* p) { return *p; }
__device__ __forceinline__ float load1(const __hip_bfloat16* p) { return __bfloat162float(*p); }
__device__ __forceinline__ void store2(float* p, float a, float b) {
    *(float2*)p = make_float2(a, b);
}
__device__ __forceinline__ void store2(__hip_bfloat16* p, float a, float b) {
    __hip_bfloat162 h;
    h.x = __float2bfloat16(a);
    h.y = __float2bfloat16(b);
    *(__hip_bfloat162*)p = h;
}

// ---------------------------------------------------------------------------
// fused SAGE layer: out[row] = X[row]@Ws + mean_neigh(X)[row]@Wn + b (+relu)
// block = 256 threads = 4 waves; wave handles 8 rows; lane owns 2 cols.
// Phase A: gather neighbor mean into LDS sH (per-lane cols, coalesced row reads)
// Phase B: self GEMM (wave-uniform row-element loads, weights in LDS)
// Phase C: neighbor GEMM (sH broadcast reads, weights in LDS)
// LDS: 64KB weights + 16KB sH = 80KB -> 2 blocks/CU.
// ---------------------------------------------------------------------------
template <typename TIN, typename TOUT>
__global__ __launch_bounds__(256, 2) void sage_layer(
    const TIN* __restrict__ X,
    const int* __restrict__ offs, const int* __restrict__ csr,
    const float* __restrict__ Ws, const float* __restrict__ Wn,
    const float* __restrict__ bias,
    TOUT* __restrict__ out, int relu) {
    __shared__ float sW[F * F];   // 64 KB
    __shared__ float sH[32 * F];  // 16 KB
    const int t = threadIdx.x;
    const int lane = t & 63;
    const int wave = t >> 6;
    const int row0 = blockIdx.x * 32 + wave * 8;
    const int c0 = lane * 2;

    // stage Ws (independent of phase A; loads overlap gather)
    for (int i = t; i < F * F / 4; i += 256)
        ((float4*)sW)[i] = ((const float4*)Ws)[i];

    // Phase A: neighbor mean -> sH
    for (int r = 0; r < 8; r++) {
        const int row = row0 + r;
        const int e0 = offs[row], e1 = offs[row + 1];
        float sx = 0.f, sy = 0.f;
        for (int e = e0; e < e1; e++) {
            const int s = csr[e];  // wave-uniform
            float2 v = load2(&X[(size_t)s * F + c0]);
            sx += v.x;
            sy += v.y;
        }
        const float inv = (e1 > e0) ? (1.0f / (float)(e1 - e0)) : 0.f;
        sH[(wave * 8 + r) * F + c0] = sx * inv;
        sH[(wave * 8 + r) * F + c0 + 1] = sy * inv;
    }
    __syncthreads();

    float accS[8][2], accN[8][2];
#pragma unroll
    for (int r = 0; r < 8; r++) {
        accS[r][0] = accS[r][1] = 0.f;
        accN[r][0] = accN[r][1] = 0.f;
    }

    // Phase B: self GEMM
#pragma unroll 2
    for (int k = 0; k < F; k++) {
        const float2 w = *(const float2*)&sW[k * F + c0];
#pragma unroll
        for (int r = 0; r < 8; r++) {
            const float a = load1(&X[(size_t)(row0 + r) * F + k]);
            accS[r][0] += a * w.x;
            accS[r][1] += a * w.y;
        }
    }
    __syncthreads();

    // restage Wn
    for (int i = t; i < F * F / 4; i += 256)
        ((float4*)sW)[i] = ((const float4*)Wn)[i];
    __syncthreads();

    // Phase C: neighbor GEMM from sH
#pragma unroll 2
    for (int k = 0; k < F; k++) {
        const float2 w = *(const float2*)&sW[k * F + c0];
#pragma unroll
        for (int r = 0; r < 8; r++) {
            const float h = sH[(wave * 8 + r) * F + k];  // broadcast
            accN[r][0] += h * w.x;
            accN[r][1] += h * w.y;
        }
    }

    const float2 bv = *(const float2*)&bias[c0];
#pragma unroll
    for (int r = 0; r < 8; r++) {
        float o0 = accS[r][0] + accN[r][0] + bv.x;
        float o1 = accS[r][1] + accN[r][1] + bv.y;
        if (relu) {
            o0 = fmaxf(o0, 0.f);
            o1 = fmaxf(o1, 0.f);
        }
        store2(&out[(size_t)(row0 + r) * F + c0], o0, o1);
    }
}

// ---------------------------------------------------------------------------
extern "C" void kernel_launch(void* const* d_in, const int* in_sizes, int n_in,
                              void* d_out, int out_size, void* d_ws, size_t ws_size,
                              hipStream_t stream) {
    const float* x = (const float*)d_in[0];
    const int* src = (const int*)d_in[1];
    const int* dst = (const int*)d_in[2];
    const float* W1s = (const float*)d_in[3];
    const float* W1n = (const float*)d_in[4];
    const float* b1 = (const float*)d_in[5];
    const float* W2s = (const float*)d_in[6];
    const float* W2n = (const float*)d_in[7];
    const float* b2 = (const float*)d_in[8];
    float* out = (float*)d_out;

    const int E = in_sizes[1];
    const int N = NN;

    // ws layout (all within ~32.8 MB — must stay small; ws_size is unknown
    // and round-1 showed >51.7MB usage corrupts neighboring allocations):
    //   cnt/cur [N] int | offs [N+1] int | bsum [128] int | csr [E] int | h1 [N*F] bf16
    int* cnt = (int*)d_ws;                 // reused as cursor
    int* offs = cnt + N;                   // N+1
    int* bsum = offs + (N + 1);            // 128
    int* csr = bsum + 128;                 // E
    __hip_bfloat16* h1 = (__hip_bfloat16*)(csr + E);

    hipMemsetAsync(cnt, 0, (size_t)N * sizeof(int), stream);
    count_kernel<<<(E + 255) / 256, 256, 0, stream>>>(dst, cnt, E);

    const int NB = (N + SCAN_B - 1) / SCAN_B;  // 98
    scanA<<<NB, SCAN_B, 0, stream>>>(cnt, offs, bsum, N);
    scanB<<<1, SCAN_B, 0, stream>>>(bsum, NB);
    scanC<<<NB, SCAN_B, 0, stream>>>(offs, bsum, cnt, N, E);
    fill_kernel<<<(E + 255) / 256, 256, 0, stream>>>(src, dst, cnt, csr, E);

    // layer 1: fp32 in, bf16 h1 out, relu
    sage_layer<float, __hip_bfloat16><<<N / 32, 256, 0, stream>>>(
        x, offs, csr, W1s, W1n, b1, h1, 1);
    // layer 2: bf16 in, fp32 out
    sage_layer<__hip_bfloat16, float><<<N / 32, 256, 0, stream>>>(
        h1, offs, csr, W2s, W2n, b2, out, 0);
}

// Round 3
// 795.311 us; speedup vs baseline: 2.1407x; 2.1407x over previous
//
#include <hip/hip_runtime.h>
#include <hip/hip_bf16.h>

#define F 128
#define NN 100000
#define SCAN_B 1024

// ---------------------------------------------------------------------------
// CSR build: cnt -> exclusive scan -> cursor fill
// ---------------------------------------------------------------------------
__global__ void count_kernel(const int* __restrict__ dst, int* __restrict__ cnt, int E) {
    int i = blockIdx.x * blockDim.x + threadIdx.x;
    if (i < E) atomicAdd(&cnt[dst[i]], 1);
}

__global__ __launch_bounds__(SCAN_B) void scanA(const int* __restrict__ cnt,
                                                int* __restrict__ offs,
                                                int* __restrict__ bsum, int n) {
    __shared__ int s[SCAN_B];
    int gid = blockIdx.x * SCAN_B + threadIdx.x;
    int v = (gid < n) ? cnt[gid] : 0;
    s[threadIdx.x] = v;
    __syncthreads();
    for (int d = 1; d < SCAN_B; d <<= 1) {
        int t = (threadIdx.x >= d) ? s[threadIdx.x - d] : 0;
        __syncthreads();
        s[threadIdx.x] += t;
        __syncthreads();
    }
    if (gid < n) offs[gid] = s[threadIdx.x] - v;  // exclusive
    if (threadIdx.x == SCAN_B - 1) bsum[blockIdx.x] = s[SCAN_B - 1];
}

__global__ __launch_bounds__(SCAN_B) void scanB(int* bsum, int nb) {
    __shared__ int s[SCAN_B];
    int v = (threadIdx.x < nb) ? bsum[threadIdx.x] : 0;
    s[threadIdx.x] = v;
    __syncthreads();
    for (int d = 1; d < SCAN_B; d <<= 1) {
        int t = (threadIdx.x >= d) ? s[threadIdx.x - d] : 0;
        __syncthreads();
        s[threadIdx.x] += t;
        __syncthreads();
    }
    if (threadIdx.x < nb) bsum[threadIdx.x] = s[threadIdx.x] - v;
}

__global__ __launch_bounds__(SCAN_B) void scanC(int* __restrict__ offs,
                                                const int* __restrict__ bsum,
                                                int* __restrict__ cur, int n, int E) {
    int gid = blockIdx.x * SCAN_B + threadIdx.x;
    if (gid < n) {
        int o = offs[gid] + bsum[blockIdx.x];
        offs[gid] = o;
        cur[gid] = o;
    }
    if (gid == n) offs[n] = E;
}

__global__ void fill_kernel(const int* __restrict__ src, const int* __restrict__ dst,
                            int* __restrict__ cur, int* __restrict__ csr, int E) {
    int i = blockIdx.x * blockDim.x + threadIdx.x;
    if (i < E) {
        int p = atomicAdd(&cur[dst[i]], 1);
        csr[p] = src[i];
    }
}

// ---------------------------------------------------------------------------
// type helpers (fp32 / bf16 node features): load 4 consecutive elems as float4
// ---------------------------------------------------------------------------
__device__ __forceinline__ float4 load4(const float* p) { return *(const float4*)p; }
__device__ __forceinline__ float4 load4(const __hip_bfloat16* p) {
    __hip_bfloat162 v0 = *(const __hip_bfloat162*)p;
    __hip_bfloat162 v1 = *(const __hip_bfloat162*)(p + 2);
    return make_float4(__bfloat162float(v0.x), __bfloat162float(v0.y),
                       __bfloat162float(v1.x), __bfloat162float(v1.y));
}
__device__ __forceinline__ void store2(float* p, float a, float b) {
    *(float2*)p = make_float2(a, b);
}
__device__ __forceinline__ void store2(__hip_bfloat16* p, float a, float b) {
    __hip_bfloat162 h;
    h.x = __float2bfloat16(a);
    h.y = __float2bfloat16(b);
    *(__hip_bfloat162*)p = h;
}

// ---------------------------------------------------------------------------
// fused SAGE layer: out[row] = X[row]@Ws + mean_neigh(X)[row]@Wn + b (+relu)
// block = 256 threads = 4 waves; wave owns 8 rows; GEMM lane owns 2 cols.
// Phase 0: cooperative coalesced copy of the block's 32 self rows -> sX (LDS)
// Phase A: neighbor-mean gather -> sH. Wave = 2 edge-slots x 32 lanes x float4
//          (2 edges per load instruction), unrolled x2 => 4 row-loads in
//          flight; halves combined with shfl_xor(32).
// Phase B: fused self+neighbor GEMM; weights streamed from global (L1/L2
//          resident, coalesced float2 per lane), sX/sH via ds_read_b64
//          broadcasts.
// LDS: 16KB sX + 16KB sH = 32KB -> 5 blocks/CU; launch_bounds caps VGPR ~102.
// ---------------------------------------------------------------------------
template <typename TIN, typename TOUT>
__global__ __launch_bounds__(256, 5) void sage_layer(
    const TIN* __restrict__ X,
    const int* __restrict__ offs, const int* __restrict__ csr,
    const float* __restrict__ Ws, const float* __restrict__ Wn,
    const float* __restrict__ bias,
    TOUT* __restrict__ out, int relu) {
    __shared__ float sX[32 * F];  // 16 KB
    __shared__ float sH[32 * F];  // 16 KB
    const int t = threadIdx.x;
    const int lane = t & 63;
    const int wave = t >> 6;
    const int brow0 = blockIdx.x * 32;
    const int row0 = brow0 + wave * 8;

    // Phase 0: stage this block's 32 self rows (contiguous in memory)
    {
        const TIN* base = X + (size_t)brow0 * F;
        for (int i = t; i < 32 * F / 4; i += 256) {
            float4 v = load4(base + i * 4);
            *(float4*)&sX[i * 4] = v;
        }
    }

    // Phase A: neighbor mean -> sH
    {
        const int eslot = lane >> 5;         // 0/1: which edge of a pair
        const int cl = lane & 31;            // 32 lanes x float4 = 512 B row
        const int c = cl * 4;
#pragma unroll 1
        for (int r = 0; r < 8; r++) {
            const int row = row0 + r;
            const int e0 = offs[row], e1 = offs[row + 1];
            float4 a0 = make_float4(0.f, 0.f, 0.f, 0.f);
            float4 a1 = make_float4(0.f, 0.f, 0.f, 0.f);
            int e = e0 + eslot;
            // main: 2 slots x 2 unroll = 4 row loads in flight per wave
            for (; e + 2 < e1; e += 4) {
                const int s0 = csr[e];
                const int s1 = csr[e + 2];
                const float4 v0 = load4(&X[(size_t)s0 * F + c]);
                const float4 v1 = load4(&X[(size_t)s1 * F + c]);
                a0.x += v0.x; a0.y += v0.y; a0.z += v0.z; a0.w += v0.w;
                a1.x += v1.x; a1.y += v1.y; a1.z += v1.z; a1.w += v1.w;
            }
            for (; e < e1; e += 2) {
                const int s0 = csr[e];
                const float4 v0 = load4(&X[(size_t)s0 * F + c]);
                a0.x += v0.x; a0.y += v0.y; a0.z += v0.z; a0.w += v0.w;
            }
            a0.x += a1.x; a0.y += a1.y; a0.z += a1.z; a0.w += a1.w;
            // combine the two half-wave edge slots
            a0.x += __shfl_xor(a0.x, 32, 64);
            a0.y += __shfl_xor(a0.y, 32, 64);
            a0.z += __shfl_xor(a0.z, 32, 64);
            a0.w += __shfl_xor(a0.w, 32, 64);
            const float inv = (e1 > e0) ? (1.0f / (float)(e1 - e0)) : 0.f;
            if (eslot == 0) {
                a0.x *= inv; a0.y *= inv; a0.z *= inv; a0.w *= inv;
                *(float4*)&sH[(wave * 8 + r) * F + c] = a0;
            }
        }
    }
    __syncthreads();

    // Phase B: fused self + neighbor GEMM
    const int c0 = lane * 2;  // each lane owns 2 output columns
    float accS[8][2], accN[8][2];
#pragma unroll
    for (int r = 0; r < 8; r++) {
        accS[r][0] = accS[r][1] = 0.f;
        accN[r][0] = accN[r][1] = 0.f;
    }
    const int wr0 = wave * 8;
#pragma unroll 2
    for (int k = 0; k < F; k += 2) {
        const float2 ws0 = *(const float2*)&Ws[k * F + c0];
        const float2 ws1 = *(const float2*)&Ws[(k + 1) * F + c0];
        const float2 wn0 = *(const float2*)&Wn[k * F + c0];
        const float2 wn1 = *(const float2*)&Wn[(k + 1) * F + c0];
#pragma unroll
        for (int r = 0; r < 8; r++) {
            const float2 a = *(const float2*)&sX[(wr0 + r) * F + k];  // broadcast
            const float2 h = *(const float2*)&sH[(wr0 + r) * F + k];  // broadcast
            accS[r][0] += a.x * ws0.x + a.y * ws1.x;
            accS[r][1] += a.x * ws0.y + a.y * ws1.y;
            accN[r][0] += h.x * wn0.x + h.y * wn1.x;
            accN[r][1] += h.x * wn0.y + h.y * wn1.y;
        }
    }

    const float2 bv = *(const float2*)&bias[c0];
#pragma unroll
    for (int r = 0; r < 8; r++) {
        float o0 = accS[r][0] + accN[r][0] + bv.x;
        float o1 = accS[r][1] + accN[r][1] + bv.y;
        if (relu) {
            o0 = fmaxf(o0, 0.f);
            o1 = fmaxf(o1, 0.f);
        }
        store2(&out[(size_t)(row0 + r) * F + c0], o0, o1);
    }
}

// ---------------------------------------------------------------------------
extern "C" void kernel_launch(void* const* d_in, const int* in_sizes, int n_in,
                              void* d_out, int out_size, void* d_ws, size_t ws_size,
                              hipStream_t stream) {
    const float* x = (const float*)d_in[0];
    const int* src = (const int*)d_in[1];
    const int* dst = (const int*)d_in[2];
    const float* W1s = (const float*)d_in[3];
    const float* W1n = (const float*)d_in[4];
    const float* b1 = (const float*)d_in[5];
    const float* W2s = (const float*)d_in[6];
    const float* W2n = (const float*)d_in[7];
    const float* b2 = (const float*)d_in[8];
    float* out = (float*)d_out;

    const int E = in_sizes[1];
    const int N = NN;

    // ws layout (~32.8 MB total — proven safe in round 2):
    //   cnt/cur [N] | offs [N+1] | bsum [128] | csr [E] | h1 [N*F] bf16
    int* cnt = (int*)d_ws;
    int* offs = cnt + N;
    int* bsum = offs + (N + 1);
    int* csr = bsum + 128;
    __hip_bfloat16* h1 = (__hip_bfloat16*)(csr + E);

    hipMemsetAsync(cnt, 0, (size_t)N * sizeof(int), stream);
    count_kernel<<<(E + 255) / 256, 256, 0, stream>>>(dst, cnt, E);

    const int NB = (N + SCAN_B - 1) / SCAN_B;  // 98
    scanA<<<NB, SCAN_B, 0, stream>>>(cnt, offs, bsum, N);
    scanB<<<1, SCAN_B, 0, stream>>>(bsum, NB);
    scanC<<<NB, SCAN_B, 0, stream>>>(offs, bsum, cnt, N, E);
    fill_kernel<<<(E + 255) / 256, 256, 0, stream>>>(src, dst, cnt, csr, E);

    // layer 1: fp32 in, bf16 h1 out, relu
    sage_layer<float, __hip_bfloat16><<<N / 32, 256, 0, stream>>>(
        x, offs, csr, W1s, W1n, b1, h1, 1);
    // layer 2: bf16 in, fp32 out
    sage_layer<__hip_bfloat16, float><<<N / 32, 256, 0, stream>>>(
        h1, offs, csr, W2s, W2n, b2, out, 0);
}

// Round 4
// 528.063 us; speedup vs baseline: 3.2240x; 1.5061x over previous
//
#include <hip/hip_runtime.h>

#define F 128
#define NN 100000
#define SCAN_B 1024
#define LD 136  // padded LDS row stride in bf16 elems (272 B, 17*16B)

typedef __attribute__((ext_vector_type(8))) short short8;   // 8 bf16 = 16 B
typedef __attribute__((ext_vector_type(4))) float f32x4;
typedef __attribute__((ext_vector_type(4))) unsigned short us4;
typedef unsigned short ushort_t;

// ---------------------------------------------------------------------------
// bf16 helpers (RNE)
// ---------------------------------------------------------------------------
__device__ __forceinline__ ushort_t f2b(float f) {
    union { float f; unsigned u; } x;
    x.f = f;
    unsigned r = x.u + 0x7fffu + ((x.u >> 16) & 1u);
    return (ushort_t)(r >> 16);
}
__device__ __forceinline__ float b2f(ushort_t u) {
    union { unsigned u; float f; } x;
    x.u = ((unsigned)u) << 16;
    return x.f;
}

// ---------------------------------------------------------------------------
// CSR build: cnt -> exclusive scan -> cursor fill (proven in rounds 2-3)
// ---------------------------------------------------------------------------
__global__ void count_kernel(const int* __restrict__ dst, int* __restrict__ cnt, int E) {
    int i = blockIdx.x * blockDim.x + threadIdx.x;
    if (i < E) atomicAdd(&cnt[dst[i]], 1);
}

__global__ __launch_bounds__(SCAN_B) void scanA(const int* __restrict__ cnt,
                                                int* __restrict__ offs,
                                                int* __restrict__ bsum, int n) {
    __shared__ int s[SCAN_B];
    int gid = blockIdx.x * SCAN_B + threadIdx.x;
    int v = (gid < n) ? cnt[gid] : 0;
    s[threadIdx.x] = v;
    __syncthreads();
    for (int d = 1; d < SCAN_B; d <<= 1) {
        int t = (threadIdx.x >= d) ? s[threadIdx.x - d] : 0;
        __syncthreads();
        s[threadIdx.x] += t;
        __syncthreads();
    }
    if (gid < n) offs[gid] = s[threadIdx.x] - v;  // exclusive
    if (threadIdx.x == SCAN_B - 1) bsum[blockIdx.x] = s[SCAN_B - 1];
}

__global__ __launch_bounds__(SCAN_B) void scanB(int* bsum, int nb) {
    __shared__ int s[SCAN_B];
    int v = (threadIdx.x < nb) ? bsum[threadIdx.x] : 0;
    s[threadIdx.x] = v;
    __syncthreads();
    for (int d = 1; d < SCAN_B; d <<= 1) {
        int t = (threadIdx.x >= d) ? s[threadIdx.x - d] : 0;
        __syncthreads();
        s[threadIdx.x] += t;
        __syncthreads();
    }
    if (threadIdx.x < nb) bsum[threadIdx.x] = s[threadIdx.x] - v;
}

__global__ __launch_bounds__(SCAN_B) void scanC(int* __restrict__ offs,
                                                const int* __restrict__ bsum,
                                                int* __restrict__ cur, int n, int E) {
    int gid = blockIdx.x * SCAN_B + threadIdx.x;
    if (gid < n) {
        int o = offs[gid] + bsum[blockIdx.x];
        offs[gid] = o;
        cur[gid] = o;
    }
    if (gid == n) offs[n] = E;
}

__global__ void fill_kernel(const int* __restrict__ src, const int* __restrict__ dst,
                            int* __restrict__ cur, int* __restrict__ csr, int E) {
    int i = blockIdx.x * blockDim.x + threadIdx.x;
    if (i < E) {
        int p = atomicAdd(&cur[dst[i]], 1);
        csr[p] = src[i];
    }
}

// ---------------------------------------------------------------------------
// prepass: fp32 -> bf16 convert (4 elems/thread)
// ---------------------------------------------------------------------------
__global__ void cvt_kernel(const float* __restrict__ X, ushort_t* __restrict__ Y, int n4) {
    int i = blockIdx.x * blockDim.x + threadIdx.x;
    if (i < n4) {
        float4 v = ((const float4*)X)[i];
        us4 o;
        o.x = f2b(v.x); o.y = f2b(v.y); o.z = f2b(v.z); o.w = f2b(v.w);
        ((us4*)Y)[i] = o;
    }
}

// ---------------------------------------------------------------------------
// prepass: W [k][n] fp32 -> WT [n][k] bf16 (128x128, 16 blocks of 32x8)
// ---------------------------------------------------------------------------
__global__ __launch_bounds__(256) void wt_kernel(const float* __restrict__ W,
                                                 ushort_t* __restrict__ WT) {
    __shared__ float tile[32][33];
    int b = blockIdx.x;
    int by = (b >> 2) * 32;  // k base
    int bx = (b & 3) * 32;   // n base
    int tx = threadIdx.x & 31, ty = threadIdx.x >> 5;  // 32 x 8
    for (int i = 0; i < 32; i += 8)
        tile[ty + i][tx] = W[(by + ty + i) * F + bx + tx];
    __syncthreads();
    for (int i = 0; i < 32; i += 8)
        WT[(bx + ty + i) * F + by + tx] = f2b(tile[tx][ty + i]);
}

// ---------------------------------------------------------------------------
// fused SAGE layer (bf16 MFMA):
//   out[row] = X[row]@Ws + mean_neigh(X)[row]@Wn + b (+relu)
// block = 256 = 4 waves; block owns 32 rows.
// Phase 0: stage 32 self rows (bf16) -> sX (padded stride LD)
// Phase A: gather. wave = 4 slots x 16 lanes; each slot owns 2 rows and
//          iterates that row's edge list, unroll 4 -> 16 independent 16-B
//          loads in flight per wave; fp32 accum, bf16 mean -> sH.
// Phase B: MFMA. wave computes 32 rows x 32-col strip: 2x2 tiles of
//          16x16x32, K=128 in 4 steps, self+neigh chained into one acc
//          (32 MFMAs/wave). A-frags from LDS, B-frags from WT (L1/L2).
// LDS 17.4 KB -> 6 blocks/CU (launch_bounds cap, VGPR <= 85).
// ---------------------------------------------------------------------------
template <typename TOUT>
__device__ __forceinline__ void store1(TOUT* p, float v);
template <> __device__ __forceinline__ void store1<float>(float* p, float v) { *p = v; }
template <> __device__ __forceinline__ void store1<ushort_t>(ushort_t* p, float v) { *p = f2b(v); }

template <typename TOUT>
__global__ __launch_bounds__(256, 6) void sage_layer(
    const ushort_t* __restrict__ Xg,
    const int* __restrict__ offs, const int* __restrict__ csr,
    const ushort_t* __restrict__ WTs, const ushort_t* __restrict__ WTn,
    const float* __restrict__ bias,
    TOUT* __restrict__ out, int relu) {
    __shared__ __align__(16) ushort_t sX[32 * LD];
    __shared__ __align__(16) ushort_t sH[32 * LD];
    const int t = threadIdx.x;
    const int lane = t & 63;
    const int wave = t >> 6;
    const int brow0 = blockIdx.x * 32;

    // Phase 0: stage self rows (32 rows x 16 chunks of 16B)
    {
        const ushort_t* base = Xg + (size_t)brow0 * F;
        for (int i = t; i < 32 * 16; i += 256) {
            int row = i >> 4, ch = i & 15;
            *(short8*)&sX[row * LD + ch * 8] = *(const short8*)&base[row * F + ch * 8];
        }
    }

    // Phase A: neighbor mean -> sH (slot-partitioned rows)
    {
        const int slot = lane >> 4;
        const int cl = lane & 15;
        const int c8 = cl * 8;
#pragma unroll
        for (int rr = 0; rr < 2; rr++) {
            const int rloc = wave * 8 + slot * 2 + rr;
            const int row = brow0 + rloc;
            const int e0 = offs[row], e1 = offs[row + 1];
            float a0[8], a1[8], a2[8], a3[8];
#pragma unroll
            for (int j = 0; j < 8; j++) { a0[j] = a1[j] = a2[j] = a3[j] = 0.f; }
            int e = e0;
            for (; e + 3 < e1; e += 4) {
                const int s0 = csr[e], s1 = csr[e + 1], s2 = csr[e + 2], s3 = csr[e + 3];
                const short8 v0 = *(const short8*)&Xg[(size_t)s0 * F + c8];
                const short8 v1 = *(const short8*)&Xg[(size_t)s1 * F + c8];
                const short8 v2 = *(const short8*)&Xg[(size_t)s2 * F + c8];
                const short8 v3 = *(const short8*)&Xg[(size_t)s3 * F + c8];
#pragma unroll
                for (int j = 0; j < 8; j++) {
                    a0[j] += b2f((ushort_t)v0[j]);
                    a1[j] += b2f((ushort_t)v1[j]);
                    a2[j] += b2f((ushort_t)v2[j]);
                    a3[j] += b2f((ushort_t)v3[j]);
                }
            }
            for (; e < e1; e++) {
                const int s0 = csr[e];
                const short8 v0 = *(const short8*)&Xg[(size_t)s0 * F + c8];
#pragma unroll
                for (int j = 0; j < 8; j++) a0[j] += b2f((ushort_t)v0[j]);
            }
            const float inv = (e1 > e0) ? (1.0f / (float)(e1 - e0)) : 0.f;
            short8 o;
#pragma unroll
            for (int j = 0; j < 8; j++)
                o[j] = (short)f2b(((a0[j] + a1[j]) + (a2[j] + a3[j])) * inv);
            *(short8*)&sH[rloc * LD + c8] = o;
        }
    }
    __syncthreads();

    // Phase B: MFMA GEMM (wave strip: 32 rows x 32 cols)
    const int q = lane >> 4, nl = lane & 15;
    const int colbase = wave * 32;
    f32x4 acc00 = (f32x4)0.f, acc01 = (f32x4)0.f, acc10 = (f32x4)0.f, acc11 = (f32x4)0.f;
#pragma unroll
    for (int ks = 0; ks < 4; ks++) {
        const int ko = ks * 32 + q * 8;
        const short8 aS0 = *(const short8*)&sX[nl * LD + ko];
        const short8 aS1 = *(const short8*)&sX[(16 + nl) * LD + ko];
        const short8 aN0 = *(const short8*)&sH[nl * LD + ko];
        const short8 aN1 = *(const short8*)&sH[(16 + nl) * LD + ko];
        const size_t bo0 = (size_t)(colbase + nl) * F + ko;
        const size_t bo1 = (size_t)(colbase + 16 + nl) * F + ko;
        const short8 bS0 = *(const short8*)&WTs[bo0];
        const short8 bS1 = *(const short8*)&WTs[bo1];
        const short8 bN0 = *(const short8*)&WTn[bo0];
        const short8 bN1 = *(const short8*)&WTn[bo1];
        acc00 = __builtin_amdgcn_mfma_f32_16x16x32_bf16(aS0, bS0, acc00, 0, 0, 0);
        acc00 = __builtin_amdgcn_mfma_f32_16x16x32_bf16(aN0, bN0, acc00, 0, 0, 0);
        acc01 = __builtin_amdgcn_mfma_f32_16x16x32_bf16(aS0, bS1, acc01, 0, 0, 0);
        acc01 = __builtin_amdgcn_mfma_f32_16x16x32_bf16(aN0, bN1, acc01, 0, 0, 0);
        acc10 = __builtin_amdgcn_mfma_f32_16x16x32_bf16(aS1, bS0, acc10, 0, 0, 0);
        acc10 = __builtin_amdgcn_mfma_f32_16x16x32_bf16(aN1, bN0, acc10, 0, 0, 0);
        acc11 = __builtin_amdgcn_mfma_f32_16x16x32_bf16(aS1, bS1, acc11, 0, 0, 0);
        acc11 = __builtin_amdgcn_mfma_f32_16x16x32_bf16(aN1, bN1, acc11, 0, 0, 0);
    }

    // Epilogue: C/D layout col=lane&15, row=(lane>>4)*4+reg
    const float b0 = bias[colbase + nl];
    const float b1 = bias[colbase + 16 + nl];
#pragma unroll
    for (int r = 0; r < 4; r++) {
        const int orow0 = brow0 + q * 4 + r;
        const int orow1 = brow0 + 16 + q * 4 + r;
        float v00 = acc00[r] + b0, v01 = acc01[r] + b1;
        float v10 = acc10[r] + b0, v11 = acc11[r] + b1;
        if (relu) {
            v00 = fmaxf(v00, 0.f); v01 = fmaxf(v01, 0.f);
            v10 = fmaxf(v10, 0.f); v11 = fmaxf(v11, 0.f);
        }
        store1<TOUT>(&out[(size_t)orow0 * F + colbase + nl], v00);
        store1<TOUT>(&out[(size_t)orow0 * F + colbase + 16 + nl], v01);
        store1<TOUT>(&out[(size_t)orow1 * F + colbase + nl], v10);
        store1<TOUT>(&out[(size_t)orow1 * F + colbase + 16 + nl], v11);
    }
}

// ---------------------------------------------------------------------------
extern "C" void kernel_launch(void* const* d_in, const int* in_sizes, int n_in,
                              void* d_out, int out_size, void* d_ws, size_t ws_size,
                              hipStream_t stream) {
    const float* x = (const float*)d_in[0];
    const int* src = (const int*)d_in[1];
    const int* dst = (const int*)d_in[2];
    const float* W1s = (const float*)d_in[3];
    const float* W1n = (const float*)d_in[4];
    const float* b1 = (const float*)d_in[5];
    const float* W2s = (const float*)d_in[6];
    const float* W2n = (const float*)d_in[7];
    const float* b2 = (const float*)d_in[8];
    float* out = (float*)d_out;

    const int E = in_sizes[1];
    const int N = NN;

    // ws layout (~33 MB; ws_size is likely ~51 MB — round-1 forensics):
    //   cnt/cur[N] | offs[N+1] | bsum[128] | csr[E] | h1[N*F] bf16 | WT[4*F*F] bf16
    int* cnt = (int*)d_ws;
    int* offs = cnt + N;
    int* bsum = offs + (N + 1);
    int* csr = bsum + 128;
    ushort_t* h1 = (ushort_t*)(csr + E);
    ushort_t* WT1s = h1 + (size_t)N * F;
    ushort_t* WT1n = WT1s + F * F;
    ushort_t* WT2s = WT1n + F * F;
    ushort_t* WT2n = WT2s + F * F;
    // x_bf16 lives in d_out: dead by the time layer 2 overwrites d_out.
    ushort_t* xb = (ushort_t*)d_out;

    hipMemsetAsync(cnt, 0, (size_t)N * sizeof(int), stream);
    count_kernel<<<(E + 255) / 256, 256, 0, stream>>>(dst, cnt, E);

    const int NB = (N + SCAN_B - 1) / SCAN_B;  // 98
    scanA<<<NB, SCAN_B, 0, stream>>>(cnt, offs, bsum, N);
    scanB<<<1, SCAN_B, 0, stream>>>(bsum, NB);
    scanC<<<NB, SCAN_B, 0, stream>>>(offs, bsum, cnt, N, E);
    fill_kernel<<<(E + 255) / 256, 256, 0, stream>>>(src, dst, cnt, csr, E);

    // prepasses: x -> bf16 (into d_out), weights -> bf16 transposed
    cvt_kernel<<<(N * F / 4 + 255) / 256, 256, 0, stream>>>(x, xb, N * F / 4);
    wt_kernel<<<16, 256, 0, stream>>>(W1s, WT1s);
    wt_kernel<<<16, 256, 0, stream>>>(W1n, WT1n);
    wt_kernel<<<16, 256, 0, stream>>>(W2s, WT2s);
    wt_kernel<<<16, 256, 0, stream>>>(W2n, WT2n);

    // layer 1: bf16 in (xb), bf16 h1 out, relu
    sage_layer<ushort_t><<<N / 32, 256, 0, stream>>>(
        xb, offs, csr, WT1s, WT1n, b1, h1, 1);
    // layer 2: bf16 in (h1), fp32 out
    sage_layer<float><<<N / 32, 256, 0, stream>>>(
        h1, offs, csr, WT2s, WT2n, b2, out, 0);
}